// Round 8
// baseline (431.882 us; speedup 1.0000x reference)
//
#include <hip/hip_runtime.h>

// Problem constants (LocalitySelfAttention): B=8, N=1024, C=1024, H=16, D=64
#define B_ 8
#define N_ 1024
#define C_ 1024
#define H_ 16
#define D_ 64

typedef __attribute__((ext_vector_type(8))) short short8v;      // 8 bf16 (MFMA frag)
typedef __attribute__((ext_vector_type(4))) float f32x4;        // MFMA acc
typedef __attribute__((ext_vector_type(4))) unsigned short ushort4v;

// fp32 -> bf16 (RNE) and back; hi/lo split captures ~16 mantissa bits
__device__ __forceinline__ unsigned short f2bf_rne(float f) {
    unsigned int u = __float_as_uint(f);
    u += 0x7FFFu + ((u >> 16) & 1u);
    return (unsigned short)(u >> 16);
}
__device__ __forceinline__ float bf2f(unsigned short h) {
    return __uint_as_float(((unsigned int)h) << 16);
}

// async global->LDS DMA, 16B per lane (dest = wave-uniform base + lane*16)
__device__ __forceinline__ void gload16(const void* g, void* l) {
    __builtin_amdgcn_global_load_lds(
        (const __attribute__((address_space(1))) void*)g,
        (__attribute__((address_space(3))) void*)l, 16, 0, 0);
}

// Inverse of LDS byte swizzle f(l) = l ^ ((l>>6 & 7)<<4) (64B rows):
// f flips bit4^=bit6, bit5^=bit7, bit6^=bit8. Inverse (unit-checked):
__device__ __forceinline__ int inv_swz(int p) {
    int l = p ^ ((p >> 2) & 0x40);   // bit6 ^= bit8
    l ^= ((l >> 6) & 3) << 4;        // bit4 ^= bit6, bit5 ^= bit7
    return l;
}

// ---------------------------------------------------------------------------
// x pre-pass: f32 -> hi/lo bf16 elementwise.
// ---------------------------------------------------------------------------
__global__ __launch_bounds__(256) void split_f32(
    const float* __restrict__ in, unsigned short* __restrict__ hi,
    unsigned short* __restrict__ lo, int n4)
{
    for (int i = blockIdx.x * 256 + threadIdx.x; i < n4; i += gridDim.x * 256) {
        const float4 v = *(const float4*)&in[(size_t)i * 4];
        const float f[4] = {v.x, v.y, v.z, v.w};
        ushort4v hv, lv;
#pragma unroll
        for (int j = 0; j < 4; ++j) {
            const unsigned short hu = f2bf_rne(f[j]);
            hv[j] = hu;
            lv[j] = f2bf_rne(f[j] - bf2f(hu));
        }
        *(ushort4v*)&hi[(size_t)i * 4] = hv;
        *(ushort4v*)&lo[(size_t)i * 4] = lv;
    }
}

// ---------------------------------------------------------------------------
// Weight pre-pass: W[K][N] f32 -> T_hi/T_lo[N][K] bf16 (convert + transpose).
// ---------------------------------------------------------------------------
__global__ __launch_bounds__(256) void convert_transpose(
    const float* __restrict__ W, unsigned short* __restrict__ T_hi,
    unsigned short* __restrict__ T_lo, int K, int N)
{
    __shared__ float tile[32][33];
    const int nb = blockIdx.x * 32, kb = blockIdx.y * 32;
    const int t = threadIdx.x;
    {
        const int kr = t >> 3, nq = (t & 7) * 4;
        const float4 v = *(const float4*)&W[(size_t)(kb + kr) * N + nb + nq];
        tile[kr][nq + 0] = v.x; tile[kr][nq + 1] = v.y;
        tile[kr][nq + 2] = v.z; tile[kr][nq + 3] = v.w;
    }
    __syncthreads();
    {
        const int nr = t >> 3, kq = (t & 7) * 4;
        ushort4v hv, lv;
#pragma unroll
        for (int j = 0; j < 4; ++j) {
            const float f = tile[kq + j][nr];
            const unsigned short hu = f2bf_rne(f);
            hv[j] = hu;
            lv[j] = f2bf_rne(f - bf2f(hu));
        }
        const size_t o = (size_t)(nb + nr) * K + kb + kq;
        *(ushort4v*)&T_hi[o] = hv;
        *(ushort4v*)&T_lo[o] = lv;
    }
}

// ---------------------------------------------------------------------------
// GEMM1: 256x256 tile, BK=32, 512 thr = 8 waves (2Mx4N), per-wave 128x64.
// bf16x3 (hi*hi + hi*lo + lo*hi), all operands pre-split, gload_lds staging
// with pre-swizzled sources, LDS 128 KB double-buffered.
// Schedule per K-tile: 4 phases, each {2x gload16 prefetch -> ds_read 2
// A-frag pairs -> setprio(1) 24 MFMA setprio(0)}; B-frags read in phase 0,
// held in VGPR; ONE __syncthreads per tile (its vmcnt0 drain is covered:
// prefetch issued 1-4 phases earlier). Emits C as bf16 hi/lo (qkv).
// ---------------------------------------------------------------------------
__global__ __launch_bounds__(512, 2) void gemm256_qkv(
    const unsigned short* __restrict__ A_hi, const unsigned short* __restrict__ A_lo,
    const unsigned short* __restrict__ Bt_hi, const unsigned short* __restrict__ Bt_lo,
    unsigned short* __restrict__ C_hi, unsigned short* __restrict__ C_lo,
    int M, int N, int K)
{
    __shared__ short AhL[2][8192];   // 32 KB each set: [cur][256 rows x 32 k]
    __shared__ short AlL[2][8192];
    __shared__ short BhL[2][8192];
    __shared__ short BlL[2][8192];
    char* const AhB = (char*)AhL;
    char* const AlB = (char*)AlL;
    char* const BhB = (char*)BhL;
    char* const BlB = (char*)BlL;

    const int tid = threadIdx.x;
    const int lane = tid & 63;
    const int w = tid >> 6;            // 0..7
    const int wm = w >> 2, wn = w & 3; // 2M x 4N
    const int bm = blockIdx.y * 256, bn = blockIdx.x * 256;
    const int l15 = lane & 15, l4 = lane >> 4;

    // staging geometry: linear LDS byte p <- global element inv_swz(p)
    int srow[2], skg[2];
#pragma unroll
    for (int i = 0; i < 2; ++i) {
        const int l = inv_swz(i * 8192 + w * 1024 + lane * 16);
        srow[i] = l >> 6;
        skg[i]  = (l >> 4) & 3;
    }
    const unsigned short *sAh[2], *sAl[2], *sBh[2], *sBl[2];
#pragma unroll
    for (int i = 0; i < 2; ++i) {
        sAh[i] = A_hi  + (size_t)(bm + srow[i]) * K + skg[i] * 8;
        sAl[i] = A_lo  + (size_t)(bm + srow[i]) * K + skg[i] * 8;
        sBh[i] = Bt_hi + (size_t)(bn + srow[i]) * K + skg[i] * 8;
        sBl[i] = Bt_lo + (size_t)(bn + srow[i]) * K + skg[i] * 8;
    }
    const int dwoff = w * 1024;  // per-wave dest byte (HW adds lane*16)

    f32x4 acc[8][4];
#pragma unroll
    for (int m = 0; m < 8; ++m)
#pragma unroll
        for (int n = 0; n < 4; ++n) acc[m][n] = (f32x4){0.f, 0.f, 0.f, 0.f};

    // prologue: stage tile 0 into buffer 0
#pragma unroll
    for (int i = 0; i < 2; ++i) {
        gload16(sAh[i], AhB + i * 8192 + dwoff);
        gload16(sAl[i], AlB + i * 8192 + dwoff);
        gload16(sBh[i], BhB + i * 8192 + dwoff);
        gload16(sBl[i], BlB + i * 8192 + dwoff);
    }
    __syncthreads();

    const int nt = K / 32;
    int cur = 0;

#define AFRAG(mi, ahv, alv)                                                    \
    {                                                                          \
        const int row = wm * 128 + (mi) * 16 + l15;                            \
        const int off = ((row * 64 + l4 * 16) ^ ((row & 7) << 4)) + cur * 16384;\
        ahv = *(const short8v*)(AhB + off);                                    \
        alv = *(const short8v*)(AlB + off);                                    \
    }
#define MFMA3(m, ahv, alv)                                                     \
    _Pragma("unroll")                                                          \
    for (int n = 0; n < 4; ++n) {                                              \
        acc[m][n] = __builtin_amdgcn_mfma_f32_16x16x32_bf16(ahv, bh[n], acc[m][n], 0, 0, 0); \
        acc[m][n] = __builtin_amdgcn_mfma_f32_16x16x32_bf16(ahv, bl[n], acc[m][n], 0, 0, 0); \
        acc[m][n] = __builtin_amdgcn_mfma_f32_16x16x32_bf16(alv, bh[n], acc[m][n], 0, 0, 0); \
    }

    for (int t = 0; t < nt; ++t) {
        const int nxt = cur ^ 1;
        const int koff = (t + 1) * 32;
        const bool pf = (t + 1 < nt);
        const int dnx = nxt * 16384 + dwoff;
        short8v bh[4], bl[4];
        short8v a0, a1, b0v, b1v;

        // ---- phase 0: prefetch Ah; read B-frags + A m=0,1; 24 MFMA ----
        if (pf) { gload16(sAh[0] + koff, AhB + dnx); gload16(sAh[1] + koff, AhB + 8192 + dnx); }
#pragma unroll
        for (int n = 0; n < 4; ++n) {
            const int row = wn * 64 + n * 16 + l15;
            const int off = ((row * 64 + l4 * 16) ^ ((row & 7) << 4)) + cur * 16384;
            bh[n] = *(const short8v*)(BhB + off);
            bl[n] = *(const short8v*)(BlB + off);
        }
        AFRAG(0, a0, b0v) AFRAG(1, a1, b1v)
        __builtin_amdgcn_s_setprio(1);
        MFMA3(0, a0, b0v) MFMA3(1, a1, b1v)
        __builtin_amdgcn_s_setprio(0);

        // ---- phase 1: prefetch Al; A m=2,3 ----
        if (pf) { gload16(sAl[0] + koff, AlB + dnx); gload16(sAl[1] + koff, AlB + 8192 + dnx); }
        AFRAG(2, a0, b0v) AFRAG(3, a1, b1v)
        __builtin_amdgcn_s_setprio(1);
        MFMA3(2, a0, b0v) MFMA3(3, a1, b1v)
        __builtin_amdgcn_s_setprio(0);

        // ---- phase 2: prefetch Bh; A m=4,5 ----
        if (pf) { gload16(sBh[0] + koff, BhB + dnx); gload16(sBh[1] + koff, BhB + 8192 + dnx); }
        AFRAG(4, a0, b0v) AFRAG(5, a1, b1v)
        __builtin_amdgcn_s_setprio(1);
        MFMA3(4, a0, b0v) MFMA3(5, a1, b1v)
        __builtin_amdgcn_s_setprio(0);

        // ---- phase 3: prefetch Bl; A m=6,7 ----
        if (pf) { gload16(sBl[0] + koff, BlB + dnx); gload16(sBl[1] + koff, BlB + 8192 + dnx); }
        AFRAG(6, a0, b0v) AFRAG(7, a1, b1v)
        __builtin_amdgcn_s_setprio(1);
        MFMA3(6, a0, b0v) MFMA3(7, a1, b1v)
        __builtin_amdgcn_s_setprio(0);

        __syncthreads();   // drains vmcnt (prefetch) + lgkm; swap buffers
        cur = nxt;
    }
#undef AFRAG
#undef MFMA3

    // ---- epilogue: C/D layout col=lane&15, row=4*(lane>>4)+reg; hi/lo out ----
#pragma unroll
    for (int n = 0; n < 4; ++n) {
        const int col = bn + wn * 64 + n * 16 + l15;
#pragma unroll
        for (int m = 0; m < 8; ++m) {
            const int row0 = bm + wm * 128 + m * 16 + l4 * 4;
#pragma unroll
            for (int r = 0; r < 4; ++r) {
                const size_t idx = (size_t)(row0 + r) * N + col;
                const float f = acc[m][n][r];
                const unsigned short hu = f2bf_rne(f);
                C_hi[idx] = hu;
                C_lo[idx] = f2bf_rne(f - bf2f(hu));
            }
        }
    }
}

// ---------------------------------------------------------------------------
// GEMM2: 128x128 bf16x3 (validated round 7; kept — 256 tile would underfill
// the grid at N=1024). f32 + bias output.
// ---------------------------------------------------------------------------
__global__ __launch_bounds__(256, 2) void gemm_split_f32out(
    const unsigned short* __restrict__ A_hi, const unsigned short* __restrict__ A_lo,
    const unsigned short* __restrict__ Bt_hi, const unsigned short* __restrict__ Bt_lo,
    const float* __restrict__ bias, float* __restrict__ Cf,
    int M, int N, int K)
{
    __shared__ short As_hi[128 * 32], As_lo[128 * 32];
    __shared__ short Bs_hi[128 * 32], Bs_lo[128 * 32];

    const int tid = threadIdx.x;
    const int lane = tid & 63;
    const int w = tid >> 6;
    const int wm = w >> 1, wn = w & 1;
    const int bm = blockIdx.y * 128, bn = blockIdx.x * 128;
    const int l15 = lane & 15, l4 = lane >> 4;

    const unsigned short *pAh[2], *pAl[2], *pBh[2], *pBl[2];
    char *dAh[2], *dAl[2], *dBh[2], *dBl[2];
#pragma unroll
    for (int i = 0; i < 2; ++i) {
        const int p = w * 2048 + i * 1024 + lane * 16;
        const int l = inv_swz(p);
        const int row = l >> 6, kg = (l >> 4) & 3;
        pAh[i] = A_hi + (size_t)(bm + row) * K + kg * 8;
        pAl[i] = A_lo + (size_t)(bm + row) * K + kg * 8;
        pBh[i] = Bt_hi + (size_t)(bn + row) * K + kg * 8;
        pBl[i] = Bt_lo + (size_t)(bn + row) * K + kg * 8;
        dAh[i] = (char*)As_hi + w * 2048 + i * 1024;
        dAl[i] = (char*)As_lo + w * 2048 + i * 1024;
        dBh[i] = (char*)Bs_hi + w * 2048 + i * 1024;
        dBl[i] = (char*)Bs_lo + w * 2048 + i * 1024;
    }

    f32x4 acc[4][4];
#pragma unroll
    for (int m = 0; m < 4; ++m)
#pragma unroll
        for (int n = 0; n < 4; ++n) acc[m][n] = (f32x4){0.f, 0.f, 0.f, 0.f};

    for (int k0 = 0; k0 < K; k0 += 32) {
#pragma unroll
        for (int i = 0; i < 2; ++i) {
            gload16(pAh[i] + k0, dAh[i]);
            gload16(pAl[i] + k0, dAl[i]);
            gload16(pBh[i] + k0, dBh[i]);
            gload16(pBl[i] + k0, dBl[i]);
        }
        __syncthreads();

        short8v ah[4], al[4], bh[4], bl[4];
#pragma unroll
        for (int m = 0; m < 4; ++m) {
            const int row = wm * 64 + m * 16 + l15;
            const int off = (row * 64 + l4 * 16) ^ ((row & 7) << 4);
            ah[m] = *(const short8v*)((char*)As_hi + off);
            al[m] = *(const short8v*)((char*)As_lo + off);
        }
#pragma unroll
        for (int n = 0; n < 4; ++n) {
            const int row = wn * 64 + n * 16 + l15;
            const int off = (row * 64 + l4 * 16) ^ ((row & 7) << 4);
            bh[n] = *(const short8v*)((char*)Bs_hi + off);
            bl[n] = *(const short8v*)((char*)Bs_lo + off);
        }

#pragma unroll
        for (int m = 0; m < 4; ++m)
#pragma unroll
            for (int n = 0; n < 4; ++n) {
                acc[m][n] = __builtin_amdgcn_mfma_f32_16x16x32_bf16(
                    ah[m], bh[n], acc[m][n], 0, 0, 0);
                acc[m][n] = __builtin_amdgcn_mfma_f32_16x16x32_bf16(
                    ah[m], bl[n], acc[m][n], 0, 0, 0);
                acc[m][n] = __builtin_amdgcn_mfma_f32_16x16x32_bf16(
                    al[m], bh[n], acc[m][n], 0, 0, 0);
            }
        __syncthreads();
    }

#pragma unroll
    for (int n = 0; n < 4; ++n) {
        const int col = bn + wn * 64 + n * 16 + l15;
        const float bv = bias ? bias[col] : 0.f;
#pragma unroll
        for (int m = 0; m < 4; ++m) {
            const int row0 = bm + wm * 64 + m * 16 + l4 * 4;
#pragma unroll
            for (int r = 0; r < 4; ++r)
                Cf[(size_t)(row0 + r) * N + col] = acc[m][n][r] + bv;
        }
    }
}

// ---------------------------------------------------------------------------
// MFMA flash attention (validated round 7, unchanged).
// ---------------------------------------------------------------------------
__global__ __launch_bounds__(256, 2) void attn_mfma(
    const unsigned short* __restrict__ qkv_hi,
    const unsigned short* __restrict__ qkv_lo,
    const float* __restrict__ scale,
    unsigned short* __restrict__ attn_hi, unsigned short* __restrict__ attn_lo)
{
    constexpr int C3 = 3 * C_;

    __shared__ short Kh[64 * 64];   // K hi [key][d], byte^=(key&7)<<4
    __shared__ short Kl[64 * 64];   // K lo
    __shared__ short Vt[64 * 64];   // V^T hi [d][key], byte^=(d&7)<<4

    const int bid = blockIdx.x;
    const int rt  = 15 - (bid >> 7);
    const int hb  = bid & 127;
    const int h   = hb & 15;
    const int b   = hb >> 4;

    const int tid  = threadIdx.x;
    const int w    = tid >> 6;
    const int lane = tid & 63;
    const int l15  = lane & 15;
    const int g    = lane >> 4;

    const float sc = scale[h];

    short8v qh[2], ql[2];
    {
        const size_t qoff =
            ((size_t)(b * N_ + rt * 64 + w * 16 + l15)) * C3 + h * D_;
#pragma unroll
        for (int t = 0; t < 2; ++t) {
            qh[t] = *(const short8v*)&qkv_hi[qoff + t * 32 + g * 8];
            ql[t] = *(const short8v*)&qkv_lo[qoff + t * 32 + g * 8];
        }
    }

    f32x4 accO[4];
#pragma unroll
    for (int n = 0; n < 4; ++n) accO[n] = (f32x4){0.f, 0.f, 0.f, 0.f};
    float m_old = -1e30f, l_old = 0.f;

    for (int jt = 0; jt <= rt; ++jt) {
        __syncthreads();

#pragma unroll
        for (int it = 0; it < 2; ++it) {
            const int u2  = tid + 256 * it;
            const int row = u2 >> 3;
            const int dq8 = u2 & 7;
            const size_t base =
                ((size_t)(b * N_ + jt * 64 + row)) * C3 + C_ + h * D_ + dq8 * 8;
            const int kbyte = (row * 128 + dq8 * 16) ^ ((row & 7) << 4);
            *(short8v*)((char*)Kh + kbyte) = *(const short8v*)&qkv_hi[base];
            *(short8v*)((char*)Kl + kbyte) = *(const short8v*)&qkv_lo[base];
        }
#pragma unroll
        for (int vt = 0; vt < 4; ++vt) {
            const int u2  = tid + 256 * vt;
            const int row = u2 >> 4;
            const int dq  = (u2 & 15) * 4;
            const size_t base =
                ((size_t)(b * N_ + jt * 64 + row)) * C3 + 2 * C_ + h * D_ + dq;
            const unsigned long long v8 = *(const unsigned long long*)&qkv_hi[base];
            unsigned short ov[4];
            ov[0] = (unsigned short)v8;
            ov[1] = (unsigned short)(v8 >> 16);
            ov[2] = (unsigned short)(v8 >> 32);
            ov[3] = (unsigned short)(v8 >> 48);
            int pv[4];
#pragma unroll
            for (int j = 0; j < 4; ++j) pv[j] = __shfl_xor((int)ov[j], 16, 64);
            const int row2 = row & ~1;
            const int odd  = row & 1;
#pragma unroll
            for (int s2 = 0; s2 < 2; ++s2) {
                const int i = odd * 2 + s2;
                const int d = dq + i;
                const unsigned int fe = odd ? (unsigned short)pv[i] : ov[i];
                const unsigned int fo = odd ? ov[i] : (unsigned short)pv[i];
                const unsigned int pack = fe | (fo << 16);
                const int vbyte = (d * 128 + row2 * 2) ^ ((d & 7) << 4);
                *(unsigned int*)((char*)Vt + vbyte) = pack;
            }
        }
        __syncthreads();

        const int kbmax = (jt == rt) ? w : 3;
        f32x4 accS[4];
#pragma unroll
        for (int kb = 0; kb < 4; ++kb) accS[kb] = (f32x4){0.f, 0.f, 0.f, 0.f};
        for (int kb = 0; kb <= kbmax; ++kb) {
#pragma unroll
            for (int t = 0; t < 2; ++t) {
                const int kbyte =
                    ((16 * kb + l15) * 128 + t * 64 + g * 16) ^ ((l15 & 7) << 4);
                const short8v kh = *(const short8v*)((const char*)Kh + kbyte);
                const short8v kl = *(const short8v*)((const char*)Kl + kbyte);
                accS[kb] = __builtin_amdgcn_mfma_f32_16x16x32_bf16(
                    kh, qh[t], accS[kb], 0, 0, 0);
                accS[kb] = __builtin_amdgcn_mfma_f32_16x16x32_bf16(
                    kh, ql[t], accS[kb], 0, 0, 0);
                accS[kb] = __builtin_amdgcn_mfma_f32_16x16x32_bf16(
                    kl, qh[t], accS[kb], 0, 0, 0);
            }
        }

        float p[16];
        float tmax = -1e30f;
#pragma unroll
        for (int kb = 0; kb < 4; ++kb) {
#pragma unroll
            for (int r = 0; r < 4; ++r) {
                float s = accS[kb][r] * sc;
                bool allow = (kb <= kbmax);
                if (jt == rt && kb == w) allow = allow && ((4 * g + r) < l15);
                s = allow ? s : -1e30f;
                p[kb * 4 + r] = s;
                tmax = fmaxf(tmax, s);
            }
        }
        tmax = fmaxf(tmax, __shfl_xor(tmax, 16, 64));
        tmax = fmaxf(tmax, __shfl_xor(tmax, 32, 64));
        const float m_new = fmaxf(m_old, tmax);
        const float alpha = __expf(m_old - m_new);
        float lsum = 0.f;
#pragma unroll
        for (int i = 0; i < 16; ++i) {
            const float pe = (p[i] > -1e29f) ? __expf(p[i] - m_new) : 0.f;
            p[i] = pe;
            lsum += pe;
        }
        lsum += __shfl_xor(lsum, 16, 64);
        lsum += __shfl_xor(lsum, 32, 64);
        l_old = alpha * l_old + lsum;
        m_old = m_new;

        unsigned int pk[4][2];
#pragma unroll
        for (int kb = 0; kb < 4; ++kb) {
            pk[kb][0] = (unsigned int)f2bf_rne(p[kb * 4 + 0]) |
                        ((unsigned int)f2bf_rne(p[kb * 4 + 1]) << 16);
            pk[kb][1] = (unsigned int)f2bf_rne(p[kb * 4 + 2]) |
                        ((unsigned int)f2bf_rne(p[kb * 4 + 3]) << 16);
        }

        float ar[4];
#pragma unroll
        for (int r = 0; r < 4; ++r) ar[r] = __shfl(alpha, 4 * g + r, 64);
#pragma unroll
        for (int n = 0; n < 4; ++n)
#pragma unroll
            for (int r = 0; r < 4; ++r) accO[n][r] *= ar[r];

        const int s0 = l15 + 16 * ((2 * g) & 3);
        const int s1 = l15 + 16 * ((2 * g + 1) & 3);
        const bool lowg = (g < 2);
#pragma unroll
        for (int t = 0; t < 2; ++t) {
            const int a0 = __shfl((int)pk[2 * t][0], s0, 64);
            const int a1 = __shfl((int)pk[2 * t][1], s0, 64);
            const int b0 = __shfl((int)pk[2 * t + 1][0], s0, 64);
            const int b1 = __shfl((int)pk[2 * t + 1][1], s0, 64);
            const int c0 = __shfl((int)pk[2 * t][0], s1, 64);
            const int c1 = __shfl((int)pk[2 * t][1], s1, 64);
            const int d0 = __shfl((int)pk[2 * t + 1][0], s1, 64);
            const int d1 = __shfl((int)pk[2 * t + 1][1], s1, 64);
            union { short8v v; int u[4]; } A;
            A.u[0] = lowg ? a0 : b0;
            A.u[1] = lowg ? a1 : b1;
            A.u[2] = lowg ? c0 : d0;
            A.u[3] = lowg ? c1 : d1;
#pragma unroll
            for (int n = 0; n < 4; ++n) {
                const int vbyte =
                    ((16 * n + l15) * 128 + t * 64 + g * 16) ^ ((l15 & 7) << 4);
                const short8v vt = *(const short8v*)((const char*)Vt + vbyte);
                accO[n] = __builtin_amdgcn_mfma_f32_16x16x32_bf16(
                    A.v, vt, accO[n], 0, 0, 0);
            }
        }
    }

    float linv[4];
#pragma unroll
    for (int r = 0; r < 4; ++r) {
        const float lr = __shfl(l_old, 4 * g + r, 64);
        linv[r] = (lr > 0.f) ? 1.f / lr : 0.f;
    }
#pragma unroll
    for (int n = 0; n < 4; ++n) {
#pragma unroll
        for (int r = 0; r < 4; ++r) {
            const float f = accO[n][r] * linv[r];
            const unsigned short hu = f2bf_rne(f);
            const unsigned short lu = f2bf_rne(f - bf2f(hu));
            const size_t idx =
                ((size_t)(b * N_ + rt * 64 + w * 16 + 4 * g + r)) * C_ +
                h * 64 + 16 * n + l15;
            attn_hi[idx] = hu;
            attn_lo[idx] = lu;
        }
    }
}

// ---------------------------------------------------------------------------
// Memory plan (unchanged from round 7; ws <= 128 MB, d_out doubles as x hi/lo).
// ---------------------------------------------------------------------------
extern "C" void kernel_launch(void* const* d_in, const int* in_sizes, int n_in,
                              void* d_out, int out_size, void* d_ws, size_t ws_size,
                              hipStream_t stream) {
    (void)in_sizes; (void)n_in; (void)out_size; (void)ws_size;
    const float* x      = (const float*)d_in[0];
    const float* w_qkv  = (const float*)d_in[1];
    const float* scale  = (const float*)d_in[2];
    const float* w_out  = (const float*)d_in[3];
    const float* b_out  = (const float*)d_in[4];
    float* out = (float*)d_out;

    char* ws = (char*)d_ws;
    unsigned short* x_hi = (unsigned short*)d_out;              // 16 MB
    unsigned short* x_lo = x_hi + (size_t)B_ * N_ * C_;         // 16 MB
    unsigned short* qkv_hi = (unsigned short*)ws;               // 48 MB
    unsigned short* qkv_lo = (unsigned short*)(ws + ((size_t)48 << 20));
    unsigned short* woutT_hi = (unsigned short*)ws;             // 2 MB (after attn)
    unsigned short* woutT_lo = (unsigned short*)(ws + ((size_t)2 << 20));
    unsigned short* wqkvT_hi = (unsigned short*)(ws + ((size_t)96 << 20));
    unsigned short* wqkvT_lo = (unsigned short*)(ws + ((size_t)102 << 20));
    unsigned short* attn_hi  = (unsigned short*)(ws + ((size_t)96 << 20));
    unsigned short* attn_lo  = (unsigned short*)(ws + ((size_t)112 << 20));

    const int M = B_ * N_;

    split_f32<<<2048, 256, 0, stream>>>(x, x_hi, x_lo, M * C_ / 4);

    convert_transpose<<<dim3(3 * C_ / 32, C_ / 32), 256, 0, stream>>>(
        w_qkv, wqkvT_hi, wqkvT_lo, C_, 3 * C_);

    gemm256_qkv<<<dim3(3 * C_ / 256, M / 256), 512, 0, stream>>>(
        x_hi, x_lo, wqkvT_hi, wqkvT_lo, qkv_hi, qkv_lo, M, 3 * C_, C_);

    attn_mfma<<<2048, 256, 0, stream>>>(qkv_hi, qkv_lo, scale, attn_hi, attn_lo);

    convert_transpose<<<dim3(C_ / 32, C_ / 32), 256, 0, stream>>>(
        w_out, woutT_hi, woutT_lo, C_, C_);

    gemm_split_f32out<<<dim3(C_ / 128, M / 128), 256, 0, stream>>>(
        attn_hi, attn_lo, woutT_hi, woutT_lo, b_out, out, M, C_, C_);
}